// Round 2
// baseline (50.325 us; speedup 1.0000x reference)
//
#include <hip/hip_runtime.h>
#include <math.h>

#define WIDTH 8192
#define NROW  2048          // B*C = 16*128
#define T4    (WIDTH / 4)   // float4 slots per row = 2048

// ---------------------------------------------------------------------------
// Probe: decide how the boolean mask was marshalled.
//   flag = 0 : int32 per element (values 0/1)
//   flag = 1 : 1 byte per element (numpy bool_)
//   flag = 2 : float32 per element (0.0 / 1.0)
// With ~95% of mask true, the first 1 KiB distinguishes these with certainty:
//   byte-bools  -> words like 0x01010101 (>1, != 0x3F800000)
//   int32 0/1   -> every word <= 1
//   float32 1.0 -> word == 0x3F800000
// ---------------------------------------------------------------------------
__global__ void detect_mask_kind(const unsigned* __restrict__ mw,
                                 int* __restrict__ flag) {
    int lid = threadIdx.x;  // one wave of 64
    int isbyte = 0, isfloat = 0;
#pragma unroll
    for (int j = 0; j < 4; ++j) {
        unsigned w = mw[lid * 4 + j];
        if (w == 0x3F800000u)      isfloat = 1;
        else if (w > 1u)           isbyte  = 1;
    }
    unsigned long long bf = __ballot(isfloat != 0);
    unsigned long long bb = __ballot(isbyte != 0);
    if (lid == 0) flag[0] = bf ? 2 : (bb ? 1 : 0);
}

// compare-exchange
#define CE(a, b) { float _lo = fminf(a, b); float _hi = fmaxf(a, b); a = _lo; b = _hi; }

__launch_bounds__(256)
__global__ void mmp_kernel(const float* __restrict__ x,
                           const void* __restrict__ mask,
                           const int* __restrict__ flag,
                           float* __restrict__ out) {
    const int bid   = blockIdx.x;
    const int row   = bid >> 3;        // 8 blocks per row
    const int chunk = bid & 7;
    const int o0    = chunk * 1024 + threadIdx.x * 4;   // first of 4 outputs
    const long base = (long)row * WIDTH;
    const int  t    = o0 >> 2;         // float4 slot within row, 0..T4-1

    // ---- load x: 12 values covering original indices o0-4 .. o0+7 ----
    const float4* x4 = (const float4*)x + (base >> 2);
    float4 A  = (t > 0)      ? x4[t - 1] : make_float4(0.f, 0.f, 0.f, 0.f);
    float4 Bv = x4[t];
    float4 Cv = (t < T4 - 1) ? x4[t + 1] : make_float4(0.f, 0.f, 0.f, 0.f);

    // ---- load mask -> 12 validity bits (bit j = index o0-4+j valid) ----
    unsigned mv = 0;
    const int kind = flag[0];          // uniform branch
    if (kind == 0) {                   // int32 mask
        const int4* m4 = (const int4*)mask + (base >> 2);
        int4 MA = (t > 0)      ? m4[t - 1] : make_int4(0, 0, 0, 0);
        int4 MB = m4[t];
        int4 MC = (t < T4 - 1) ? m4[t + 1] : make_int4(0, 0, 0, 0);
        mv = (unsigned)((MA.x != 0)        | ((MA.y != 0) << 1) |
                        ((MA.z != 0) << 2) | ((MA.w != 0) << 3) |
                        ((MB.x != 0) << 4) | ((MB.y != 0) << 5) |
                        ((MB.z != 0) << 6) | ((MB.w != 0) << 7) |
                        ((MC.x != 0) << 8) | ((MC.y != 0) << 9) |
                        ((MC.z != 0) <<10) | ((MC.w != 0) <<11));
    } else if (kind == 1) {            // byte mask (numpy bool_)
        const unsigned* mw = (const unsigned*)mask + (base >> 2);
        unsigned wA = (t > 0)      ? mw[t - 1] : 0u;
        unsigned wB = mw[t];
        unsigned wC = (t < T4 - 1) ? mw[t + 1] : 0u;
        mv = (unsigned)(((((wA      ) & 0xFFu) != 0)       ) |
                        ((((wA >> 8) & 0xFFu) != 0) << 1)    |
                        ((((wA >>16) & 0xFFu) != 0) << 2)    |
                        ((((wA >>24) & 0xFFu) != 0) << 3)    |
                        ((((wB      ) & 0xFFu) != 0) << 4)   |
                        ((((wB >> 8) & 0xFFu) != 0) << 5)    |
                        ((((wB >>16) & 0xFFu) != 0) << 6)    |
                        ((((wB >>24) & 0xFFu) != 0) << 7)    |
                        ((((wC      ) & 0xFFu) != 0) << 8)   |
                        ((((wC >> 8) & 0xFFu) != 0) << 9)    |
                        ((((wC >>16) & 0xFFu) != 0) << 10)   |
                        ((((wC >>24) & 0xFFu) != 0) << 11));
    } else {                           // float32 mask
        const float4* m4 = (const float4*)mask + (base >> 2);
        float4 MA = (t > 0)      ? m4[t - 1] : make_float4(0.f, 0.f, 0.f, 0.f);
        float4 MB = m4[t];
        float4 MC = (t < T4 - 1) ? m4[t + 1] : make_float4(0.f, 0.f, 0.f, 0.f);
        mv = (unsigned)((MA.x != 0.f)        | ((MA.y != 0.f) << 1) |
                        ((MA.z != 0.f) << 2) | ((MA.w != 0.f) << 3) |
                        ((MB.x != 0.f) << 4) | ((MB.y != 0.f) << 5) |
                        ((MB.z != 0.f) << 6) | ((MB.w != 0.f) << 7) |
                        ((MC.x != 0.f) << 8) | ((MC.y != 0.f) << 9) |
                        ((MC.z != 0.f) <<10) | ((MC.w != 0.f) <<11));
    }

    const float xv[12] = { A.x, A.y, A.z, A.w,
                           Bv.x, Bv.y, Bv.z, Bv.w,
                           Cv.x, Cv.y, Cv.z, Cv.w };

    const float INF = __builtin_inff();
    float r0 = 0.f, r1 = 0.f, r2 = 0.f, r3 = 0.f;

#pragma unroll
    for (int i = 0; i < 4; ++i) {
        const unsigned wb = (mv >> (i + 1)) & 0x7Fu;   // 7 validity bits
        const int n = __popc(wb);
        float v0 = (wb & 1u)   ? xv[i + 1] : INF;
        float v1 = (wb & 2u)   ? xv[i + 2] : INF;
        float v2 = (wb & 4u)   ? xv[i + 3] : INF;
        float v3 = (wb & 8u)   ? xv[i + 4] : INF;
        float v4 = (wb & 16u)  ? xv[i + 5] : INF;
        float v5 = (wb & 32u)  ? xv[i + 6] : INF;
        float v6 = (wb & 64u)  ? xv[i + 7] : INF;

        // odd-even transposition sort, 7 rounds — provably correct for 7 elems
#pragma unroll
        for (int rr = 0; rr < 7; ++rr) {
            if ((rr & 1) == 0) { CE(v0, v1); CE(v2, v3); CE(v4, v5); }
            else               { CE(v1, v2); CE(v3, v4); CE(v5, v6); }
        }

        const int k = (n - 1) >> 1;                    // 0..3 for n>=1
        float med = (k == 0) ? v0 : (k == 1) ? v1 : (k == 2) ? v2 : v3;
        med = (n == 0) ? __builtin_nanf("") : med;
        if (i == 0) r0 = med; else if (i == 1) r1 = med;
        else if (i == 2) r2 = med; else r3 = med;
    }

    float4* o4 = (float4*)out + (base >> 2);
    o4[t] = make_float4(r0, r1, r2, r3);
}

extern "C" void kernel_launch(void* const* d_in, const int* in_sizes, int n_in,
                              void* d_out, int out_size, void* d_ws, size_t ws_size,
                              hipStream_t stream) {
    const float* x    = (const float*)d_in[0];
    const void*  mask = d_in[1];
    int*   flag = (int*)d_ws;
    float* outp = (float*)d_out;

    detect_mask_kind<<<1, 64, 0, stream>>>((const unsigned*)mask, flag);
    mmp_kernel<<<NROW * 8, 256, 0, stream>>>(x, mask, flag, outp);
}